// Round 2
// baseline (405.460 us; speedup 1.0000x reference)
//
#include <hip/hip_runtime.h>

// HGCN forward, MI355X. Key observation: reference returns
//   out + 0.0 * sum(h_all)  -> the hyperbolic branch is an exact zero
// (all its intermediates are clipped/finite), so the live path is only:
//   temporal attention #2 (N-reductions -> 12x12 softmax),
//   x @ At2 per node, 1x3 conv over T, raw flat-order-preserving reshape.
// ALL tensors are float32 (per the reference dtypes; round-1 NaN proved the
// bf16 assumption wrong).

#define NN   8000
#define TT   12
#define FDIM 5

// ---------------------------------------------------------------------------
// Kernel A: reduce over n into ws:
//   ws[0:60]   L[t*5+f] = sum_n x[n,t,f] * U1[n]
//   ws[60:120] M[f*12+t] = sum_n U2[f,n] * rhs[n,t],
//              rhs[n,t] = sum_f' U3[f'] * x[n,t,f']
// One thread per n; wave(64)-shuffle reduce; 1 atomicAdd per wave per value.
// ---------------------------------------------------------------------------
__global__ __launch_bounds__(256) void k_reduce(
    const float* __restrict__ x,    // (N,T,F)
    const float* __restrict__ U1,   // (N,)
    const float* __restrict__ U2,   // (F,N)
    const float* __restrict__ U3,   // (F,)
    float* __restrict__ ws)
{
    const int tid  = threadIdx.x;
    const int n    = blockIdx.x * 256 + tid;
    const int lane = tid & 63;
    const bool act = (n < NN);

    float xv[TT * FDIM];
    float u1 = 0.f;
    float u2[FDIM];
#pragma unroll
    for (int f = 0; f < FDIM; ++f) u2[f] = 0.f;

    if (act) {
        const float4* xp = (const float4*)(x + (size_t)n * TT * FDIM); // 240B rows, 16B-aligned
#pragma unroll
        for (int i = 0; i < 15; ++i) {
            float4 d = xp[i];
            xv[i * 4 + 0] = d.x; xv[i * 4 + 1] = d.y;
            xv[i * 4 + 2] = d.z; xv[i * 4 + 3] = d.w;
        }
        u1 = U1[n];
#pragma unroll
        for (int f = 0; f < FDIM; ++f) u2[f] = U2[f * NN + n];
    } else {
#pragma unroll
        for (int i = 0; i < TT * FDIM; ++i) xv[i] = 0.f;
    }

    float u3[FDIM];
#pragma unroll
    for (int f = 0; f < FDIM; ++f) u3[f] = U3[f];

    float rhs[TT];
#pragma unroll
    for (int t = 0; t < TT; ++t) {
        float s = 0.f;
#pragma unroll
        for (int f = 0; f < FDIM; ++f) s += u3[f] * xv[t * FDIM + f];
        rhs[t] = s;
    }

    // L reduction
#pragma unroll
    for (int t = 0; t < TT; ++t) {
#pragma unroll
        for (int f = 0; f < FDIM; ++f) {
            float v = xv[t * FDIM + f] * u1;
#pragma unroll
            for (int off = 32; off; off >>= 1) v += __shfl_down(v, off);
            if (lane == 0) atomicAdd(&ws[t * FDIM + f], v);
        }
    }
    // M reduction
#pragma unroll
    for (int f = 0; f < FDIM; ++f) {
#pragma unroll
        for (int t = 0; t < TT; ++t) {
            float v = u2[f] * rhs[t];
#pragma unroll
            for (int off = 32; off; off >>= 1) v += __shfl_down(v, off);
            if (lane == 0) atomicAdd(&ws[60 + f * TT + t], v);
        }
    }
}

// ---------------------------------------------------------------------------
// Kernel B: every block redundantly computes the 12x12 attention in LDS
// (~2k FLOPs, avoids a third launch), then one thread per n:
// x2 = x @ At, 1x3 conv over T (pad 1), store.
// Output flat layout (raw reshape): out[o*N*T + n*T + t].
// ---------------------------------------------------------------------------
__global__ __launch_bounds__(256) void k_main(
    const float* __restrict__ x,    // (N,T,F)
    const float* __restrict__ be,   // (1,T,T)
    const float* __restrict__ Ve,   // (T,T)
    const float* __restrict__ cw,   // (F,F,1,3)
    const float* __restrict__ cb,   // (F,)
    const float* __restrict__ ws,
    float*       __restrict__ out)  // (F,N,T) flat
{
    __shared__ float sE[TT][TT];   // scratch: E
    __shared__ float sAt[TT][TT];  // sigmoid scratch, then final attention
    __shared__ float sW[FDIM][FDIM][3];
    __shared__ float sB[FDIM];
    __shared__ float sL[60];       // L
    __shared__ float sM[60];       // M

    const int tid = threadIdx.x;

    if (tid < 60)        sL[tid]      = ws[tid];
    else if (tid < 120)  sM[tid - 60] = ws[tid];
    if (tid >= 128 && tid < 203) {
        int q = tid - 128;                 // 75 conv weights, (o,i,0,k) flat
        sW[q / 15][(q % 15) / 3][q % 3] = cw[q];
    }
    if (tid >= 208 && tid < 213) sB[tid - 208] = cb[tid - 208];
    __syncthreads();

    // S = sigmoid(prod + be) into sAt (scratch)
    if (tid < 144) {
        int k = tid / TT, j = tid % TT;
        float p = 0.f;
#pragma unroll
        for (int f = 0; f < FDIM; ++f) p += sL[k * FDIM + f] * sM[f * TT + j];
        p += be[tid];
        sAt[k][j] = 1.f / (1.f + __expf(-p));
    }
    __syncthreads();

    // E = Ve @ S
    if (tid < 144) {
        int i = tid / TT, j = tid % TT;
        float e = 0.f;
#pragma unroll
        for (int k = 0; k < TT; ++k) e += Ve[i * TT + k] * sAt[k][j];
        sE[i][j] = e;
    }
    __syncthreads();

    // softmax over axis i (per column j) -> sAt = attention
    if (tid < TT) {
        int j = tid;
        float m = -1e30f;
#pragma unroll
        for (int i = 0; i < TT; ++i) m = fmaxf(m, sE[i][j]);
        float ex[TT], s = 0.f;
#pragma unroll
        for (int i = 0; i < TT; ++i) { ex[i] = __expf(sE[i][j] - m); s += ex[i]; }
        float inv = 1.f / s;
#pragma unroll
        for (int i = 0; i < TT; ++i) sAt[i][j] = ex[i] * inv;
    }
    __syncthreads();

    const int n = blockIdx.x * 256 + tid;
    if (n >= NN) return;

    float xv[TT * FDIM];
    {
        const float4* xp = (const float4*)(x + (size_t)n * TT * FDIM);
#pragma unroll
        for (int i = 0; i < 15; ++i) {
            float4 d = xp[i];
            xv[i * 4 + 0] = d.x; xv[i * 4 + 1] = d.y;
            xv[i * 4 + 2] = d.z; xv[i * 4 + 3] = d.w;
        }
    }

    // x2[f][t] = sum_t' x[n,t',f] * At[t'][t]
    float x2[FDIM][TT];
#pragma unroll
    for (int f = 0; f < FDIM; ++f) {
#pragma unroll
        for (int t = 0; t < TT; ++t) {
            float s = 0.f;
#pragma unroll
            for (int tp = 0; tp < TT; ++tp) s += xv[tp * FDIM + f] * sAt[tp][t];
            x2[f][t] = s;
        }
    }

    // conv 1x3 over T (pad 1) + bias; store as 3x float4 per (o,n) row
#pragma unroll
    for (int o = 0; o < FDIM; ++o) {
        float res[TT];
#pragma unroll
        for (int t = 0; t < TT; ++t) {
            float acc = sB[o];
#pragma unroll
            for (int i = 0; i < FDIM; ++i) {
                if (t > 0)      acc += sW[o][i][0] * x2[i][t - 1];
                                acc += sW[o][i][1] * x2[i][t];
                if (t < TT - 1) acc += sW[o][i][2] * x2[i][t + 1];
            }
            res[t] = acc;
        }
        float4* op = (float4*)(out + (size_t)o * NN * TT + (size_t)n * TT);
#pragma unroll
        for (int q = 0; q < 3; ++q)
            op[q] = make_float4(res[4 * q], res[4 * q + 1], res[4 * q + 2], res[4 * q + 3]);
    }
}

extern "C" void kernel_launch(void* const* d_in, const int* in_sizes, int n_in,
                              void* d_out, int out_size, void* d_ws, size_t ws_size,
                              hipStream_t stream) {
    // setup_inputs order:
    // 0:x 1:adj 2:U1_1 3:U2_1 4:U3_1 5:be_1 6:Ve_1
    // 7:U1_2 8:U2_2 9:U3_2 10:be_2 11:Ve_2
    // 12:conv1_w 13:conv1_b 14:conv2_w 15:conv2_b 16:W_hgc 17:b_hgc
    const float* x  = (const float*)d_in[0];
    const float* U1 = (const float*)d_in[7];
    const float* U2 = (const float*)d_in[8];
    const float* U3 = (const float*)d_in[9];
    const float* be = (const float*)d_in[10];
    const float* Ve = (const float*)d_in[11];
    const float* cw = (const float*)d_in[14];
    const float* cb = (const float*)d_in[15];
    float* ws  = (float*)d_ws;
    float* out = (float*)d_out;

    hipMemsetAsync(d_ws, 0, 120 * sizeof(float), stream);

    dim3 grid((NN + 255) / 256);
    k_reduce<<<grid, 256, 0, stream>>>(x, U1, U2, U3, ws);
    k_main<<<grid, 256, 0, stream>>>(x, be, Ve, cw, cb, ws, out);
}

// Round 4
// 346.295 us; speedup vs baseline: 1.1709x; 1.1709x over previous
//
#include <hip/hip_runtime.h>

// HGCN forward, MI355X — 2-dispatch deterministic version.
//
// Reference returns out + 0.0*sum(h_all): the hyperbolic branch is an exact
// zero (all intermediates clipped/finite), so the live path is:
//   temporal attention #2 (N-reductions -> 12x12 softmax),
//   x @ At2 per node, 1x3 conv over T, flat-order-preserving reshape.
//
// History: R2 (memset + atomics + 2 kernels) PASSED at 405 us. R3 (fused
// single kernel) failed post-timing divergence (unexplained). This round
// returns to the R2 structure but removes the memset dispatch and the
// atomics: each k_reduce block writes 120 partial sums to its own ws slot
// (fully written every call -> no init needed, deterministic), and k_main
// sums the 32 partials during staging.
//
// dur_us is dominated (~380 us) by harness restore/poison fills (1 GB ws
// poison at ~155 us); our controllable slice is the ~15-25 us of kernel work.

#define NN   8000
#define TT   12
#define FDIM 5
#define NBLK 32   // (NN + 255) / 256

// ---------------------------------------------------------------------------
// Kernel A: per-block partial reduction over n.
//   slot[blk][0:60]   partial L[t*5+f]  = sum_{n in blk} x[n,t,f] * U1[n]
//   slot[blk][60:120] partial M[f*12+t] = sum_{n in blk} U2[f,n] * rhs[n,t],
//                     rhs[n,t] = sum_f' U3[f'] * x[n,t,f']
// One thread per n; wave(64)-shuffle reduce; cross-wave combine in LDS;
// block writes ws[blk*120 .. blk*120+120). No atomics, no init required.
// ---------------------------------------------------------------------------
__global__ __launch_bounds__(256) void k_reduce(
    const float* __restrict__ x,    // (N,T,F)
    const float* __restrict__ U1,   // (N,)
    const float* __restrict__ U2,   // (F,N)
    const float* __restrict__ U3,   // (F,)
    float* __restrict__ ws)         // (NBLK, 120) partials
{
    __shared__ float red[4][120];

    const int tid  = threadIdx.x;
    const int n    = blockIdx.x * 256 + tid;
    const int lane = tid & 63;
    const int wave = tid >> 6;
    const bool act = (n < NN);

    float xv[TT * FDIM];
    float u1 = 0.f;
    float u2[FDIM];
#pragma unroll
    for (int f = 0; f < FDIM; ++f) u2[f] = 0.f;

    if (act) {
        const float4* xp = (const float4*)(x + (size_t)n * TT * FDIM); // 240B rows, 16B-aligned
#pragma unroll
        for (int i = 0; i < 15; ++i) {
            float4 d = xp[i];
            xv[i * 4 + 0] = d.x; xv[i * 4 + 1] = d.y;
            xv[i * 4 + 2] = d.z; xv[i * 4 + 3] = d.w;
        }
        u1 = U1[n];
#pragma unroll
        for (int f = 0; f < FDIM; ++f) u2[f] = U2[f * NN + n];
    } else {
#pragma unroll
        for (int i = 0; i < TT * FDIM; ++i) xv[i] = 0.f;
    }

    float u3[FDIM];
#pragma unroll
    for (int f = 0; f < FDIM; ++f) u3[f] = U3[f];

    float rhs[TT];
#pragma unroll
    for (int t = 0; t < TT; ++t) {
        float s = 0.f;
#pragma unroll
        for (int f = 0; f < FDIM; ++f) s += u3[f] * xv[t * FDIM + f];
        rhs[t] = s;
    }

    // L partials (values 0..59)
#pragma unroll
    for (int v = 0; v < 60; ++v) {
        float s = xv[v] * u1;
#pragma unroll
        for (int off = 32; off; off >>= 1) s += __shfl_down(s, off);
        if (lane == 0) red[wave][v] = s;
    }
    // M partials (values 60..119), layout 60 + f*12 + t
#pragma unroll
    for (int f = 0; f < FDIM; ++f) {
#pragma unroll
        for (int t = 0; t < TT; ++t) {
            float s = u2[f] * rhs[t];
#pragma unroll
            for (int off = 32; off; off >>= 1) s += __shfl_down(s, off);
            if (lane == 0) red[wave][60 + f * TT + t] = s;
        }
    }
    __syncthreads();
    if (tid < 120)
        ws[blockIdx.x * 120 + tid] =
            red[0][tid] + red[1][tid] + red[2][tid] + red[3][tid];
}

// ---------------------------------------------------------------------------
// Kernel B: every block sums the 32 partial slots (deterministic), builds the
// 12x12 attention in LDS, then one thread per n: x2 = x @ At, 1x3 conv over T
// (pad 1), store. Output flat layout (raw reshape): out[o*N*T + n*T + t].
// ---------------------------------------------------------------------------
__global__ __launch_bounds__(256) void k_main(
    const float* __restrict__ x,    // (N,T,F)
    const float* __restrict__ be,   // (1,T,T)
    const float* __restrict__ Ve,   // (T,T)
    const float* __restrict__ cw,   // (F,F,1,3)
    const float* __restrict__ cb,   // (F,)
    const float* __restrict__ ws,   // (NBLK, 120) partials
    float*       __restrict__ out)  // (F,N,T) flat
{
    __shared__ float sE[TT][TT];   // scratch: E
    __shared__ float sAt[TT][TT];  // sigmoid scratch, then final attention
    __shared__ float sW[FDIM][FDIM][3];
    __shared__ float sB[FDIM];
    __shared__ float sL[60];       // L
    __shared__ float sM[60];       // M

    const int tid = threadIdx.x;

    if (tid < 120) {
        float s = 0.f;
#pragma unroll
        for (int b = 0; b < NBLK; ++b) s += ws[b * 120 + tid];
        if (tid < 60) sL[tid] = s;
        else          sM[tid - 60] = s;
    }
    if (tid >= 128 && tid < 203) {
        int q = tid - 128;                 // 75 conv weights, (o,i,0,k) flat
        sW[q / 15][(q % 15) / 3][q % 3] = cw[q];
    }
    if (tid >= 208 && tid < 213) sB[tid - 208] = cb[tid - 208];
    __syncthreads();

    // S = sigmoid(L @ M + be) into sAt (scratch)
    if (tid < 144) {
        int k = tid / TT, j = tid % TT;
        float p = 0.f;
#pragma unroll
        for (int f = 0; f < FDIM; ++f) p += sL[k * FDIM + f] * sM[f * TT + j];
        p += be[tid];
        sAt[k][j] = 1.f / (1.f + __expf(-p));
    }
    __syncthreads();

    // E = Ve @ S
    if (tid < 144) {
        int i = tid / TT, j = tid % TT;
        float e = 0.f;
#pragma unroll
        for (int k = 0; k < TT; ++k) e += Ve[i * TT + k] * sAt[k][j];
        sE[i][j] = e;
    }
    __syncthreads();

    // softmax over axis i (per column j) -> sAt = attention
    if (tid < TT) {
        int j = tid;
        float m = -1e30f;
#pragma unroll
        for (int i = 0; i < TT; ++i) m = fmaxf(m, sE[i][j]);
        float ex[TT], s = 0.f;
#pragma unroll
        for (int i = 0; i < TT; ++i) { ex[i] = __expf(sE[i][j] - m); s += ex[i]; }
        float inv = 1.f / s;
#pragma unroll
        for (int i = 0; i < TT; ++i) sAt[i][j] = ex[i] * inv;
    }
    __syncthreads();

    const int n = blockIdx.x * 256 + tid;
    if (n >= NN) return;

    float xv[TT * FDIM];
    {
        const float4* xp = (const float4*)(x + (size_t)n * TT * FDIM);
#pragma unroll
        for (int i = 0; i < 15; ++i) {
            float4 d = xp[i];
            xv[i * 4 + 0] = d.x; xv[i * 4 + 1] = d.y;
            xv[i * 4 + 2] = d.z; xv[i * 4 + 3] = d.w;
        }
    }

    // x2[f][t] = sum_t' x[n,t',f] * At[t'][t]
    float x2[FDIM][TT];
#pragma unroll
    for (int f = 0; f < FDIM; ++f) {
#pragma unroll
        for (int t = 0; t < TT; ++t) {
            float s = 0.f;
#pragma unroll
            for (int tp = 0; tp < TT; ++tp) s += xv[tp * FDIM + f] * sAt[tp][t];
            x2[f][t] = s;
        }
    }

    // conv 1x3 over T (pad 1) + bias; 3x float4 stores per (o,n) row
#pragma unroll
    for (int o = 0; o < FDIM; ++o) {
        float res[TT];
#pragma unroll
        for (int t = 0; t < TT; ++t) {
            float a = sB[o];
#pragma unroll
            for (int i = 0; i < FDIM; ++i) {
                if (t > 0)      a += sW[o][i][0] * x2[i][t - 1];
                                a += sW[o][i][1] * x2[i][t];
                if (t < TT - 1) a += sW[o][i][2] * x2[i][t + 1];
            }
            res[t] = a;
        }
        float4* op = (float4*)(out + (size_t)o * NN * TT + (size_t)n * TT);
#pragma unroll
        for (int q = 0; q < 3; ++q)
            op[q] = make_float4(res[4 * q], res[4 * q + 1], res[4 * q + 2], res[4 * q + 3]);
    }
}

extern "C" void kernel_launch(void* const* d_in, const int* in_sizes, int n_in,
                              void* d_out, int out_size, void* d_ws, size_t ws_size,
                              hipStream_t stream) {
    // setup_inputs order:
    // 0:x 1:adj 2:U1_1 3:U2_1 4:U3_1 5:be_1 6:Ve_1
    // 7:U1_2 8:U2_2 9:U3_2 10:be_2 11:Ve_2
    // 12:conv1_w 13:conv1_b 14:conv2_w 15:conv2_b 16:W_hgc 17:b_hgc
    const float* x  = (const float*)d_in[0];
    const float* U1 = (const float*)d_in[7];
    const float* U2 = (const float*)d_in[8];
    const float* U3 = (const float*)d_in[9];
    const float* be = (const float*)d_in[10];
    const float* Ve = (const float*)d_in[11];
    const float* cw = (const float*)d_in[14];
    const float* cb = (const float*)d_in[15];
    float* ws  = (float*)d_ws;
    float* out = (float*)d_out;

    dim3 grid(NBLK);
    k_reduce<<<grid, 256, 0, stream>>>(x, U1, U2, U3, ws);
    k_main<<<grid, 256, 0, stream>>>(x, be, Ve, cw, cb, ws, out);
}